// Round 1
// baseline (535.498 us; speedup 1.0000x reference)
//
#include <hip/hip_runtime.h>

#define N_NODES 50000
#define N_EDGES 800000
#define CH 64
#define N_REL 8
#define N_BASES 4

// Computes, for a 32-row tile of h:
//   xb[n][ch] = float4( (h @ basis_b)[n][ch] for b=0..3 )   layout [N][64] of float4
//   agg[n][ch] = (h @ root)[n][ch] + bias[ch]               (initializes aggregation buffer)
__global__ __launch_bounds__(256) void gemm_xb_root(
    const float* __restrict__ h,      // [N,64]
    const float* __restrict__ basis,  // [4,64,64] (layer slice)
    const float* __restrict__ root,   // [64,64]   (layer slice)
    const float* __restrict__ bias,   // [64]      (layer slice)
    float4* __restrict__ xb,          // [N*64] float4
    float* __restrict__ agg)          // [N,64]
{
    __shared__ float hs[32 * 64];
    const int tx = threadIdx.x;          // 0..63 = output channel
    const int ty = threadIdx.y;          // 0..3  = wave id
    const int tid = ty * 64 + tx;
    const int n0 = blockIdx.x * 32;

    // stage 32x64 h tile (coalesced)
    #pragma unroll
    for (int i = 0; i < 8; ++i) {
        int idx = i * 256 + tid;
        int r = idx >> 6, c = idx & 63;
        int n = n0 + r;
        hs[idx] = (n < N_NODES) ? h[n * 64 + c] : 0.f;
    }
    __syncthreads();

    float acc[5][8];
    #pragma unroll
    for (int b = 0; b < 5; ++b)
        #pragma unroll
        for (int r = 0; r < 8; ++r) acc[b][r] = 0.f;

    const int rbase = ty * 8;
    for (int k = 0; k < 64; ++k) {
        float w0 = basis[0 * 4096 + k * 64 + tx];
        float w1 = basis[1 * 4096 + k * 64 + tx];
        float w2 = basis[2 * 4096 + k * 64 + tx];
        float w3 = basis[3 * 4096 + k * 64 + tx];
        float wr = root[k * 64 + tx];
        #pragma unroll
        for (int r = 0; r < 8; ++r) {
            float hv = hs[(rbase + r) * 64 + k];  // wave-broadcast LDS read
            acc[0][r] = fmaf(hv, w0, acc[0][r]);
            acc[1][r] = fmaf(hv, w1, acc[1][r]);
            acc[2][r] = fmaf(hv, w2, acc[2][r]);
            acc[3][r] = fmaf(hv, w3, acc[3][r]);
            acc[4][r] = fmaf(hv, wr, acc[4][r]);
        }
    }

    float bv = bias[tx];
    #pragma unroll
    for (int r = 0; r < 8; ++r) {
        int n = n0 + rbase + r;
        if (n < N_NODES) {
            xb[n * 64 + tx]  = make_float4(acc[0][r], acc[1][r], acc[2][r], acc[3][r]);
            agg[n * 64 + tx] = acc[4][r] + bv;
        }
    }
}

// One wave (64 lanes = 64 channels) per edge:
//   c[b]   = sum_r ea[e,r] * att[r,b]
//   msg    = dot(c, xb[src][lane])      (float4)
//   atomicAdd(agg[dst][lane], msg)
__global__ __launch_bounds__(256) void edge_scatter(
    const int* __restrict__ ei,       // [2, E] int32: row0 = src, row1 = dst
    const float* __restrict__ ea,     // [E, 8]
    const float* __restrict__ att,    // [8, 4]  (layer slice)
    const float4* __restrict__ xb,    // [N*64]
    float* __restrict__ agg)          // [N,64]
{
    int gid = blockIdx.x * 256 + threadIdx.x;
    int e = gid >> 6;
    int lane = threadIdx.x & 63;
    if (e >= N_EDGES) return;

    int src = ei[e];
    int dst = ei[N_EDGES + e];

    const float4* eav = (const float4*)(ea + e * 8);
    float4 ea0 = eav[0], ea1 = eav[1];
    float earr[8] = {ea0.x, ea0.y, ea0.z, ea0.w, ea1.x, ea1.y, ea1.z, ea1.w};

    float c0 = 0.f, c1 = 0.f, c2 = 0.f, c3 = 0.f;
    #pragma unroll
    for (int r = 0; r < 8; ++r) {
        float4 a = ((const float4*)att)[r];   // broadcast, L2-resident
        c0 = fmaf(earr[r], a.x, c0);
        c1 = fmaf(earr[r], a.y, c1);
        c2 = fmaf(earr[r], a.z, c2);
        c3 = fmaf(earr[r], a.w, c3);
    }

    float4 v = xb[src * 64 + lane];           // wave reads contiguous 1KB
    float msg = c0 * v.x + c1 * v.y + c2 * v.z + c3 * v.w;
    atomicAdd(&agg[dst * 64 + lane], msg);
}

__global__ __launch_bounds__(256) void relu_k(float4* __restrict__ p, int n4)
{
    int i = blockIdx.x * 256 + threadIdx.x;
    if (i < n4) {
        float4 v = p[i];
        v.x = fmaxf(v.x, 0.f);
        v.y = fmaxf(v.y, 0.f);
        v.z = fmaxf(v.z, 0.f);
        v.w = fmaxf(v.w, 0.f);
        p[i] = v;
    }
}

extern "C" void kernel_launch(void* const* d_in, const int* in_sizes, int n_in,
                              void* d_out, int out_size, void* d_ws, size_t ws_size,
                              hipStream_t stream) {
    const float* x     = (const float*)d_in[0];
    const int*   ei    = (const int*)d_in[1];
    const float* ea    = (const float*)d_in[2];
    const float* basis = (const float*)d_in[3];  // [2,4,64,64]
    const float* att   = (const float*)d_in[4];  // [2,8,4]
    const float* root  = (const float*)d_in[5];  // [2,64,64]
    const float* bias  = (const float*)d_in[6];  // [2,64]
    float* out = (float*)d_out;

    float*  h1 = (float*)d_ws;                                   // 50000*64 floats = 12.8 MB
    float4* xb = (float4*)((char*)d_ws + (size_t)N_NODES * 64 * 4); // 50000*64 float4 = 51.2 MB

    dim3 gemm_grid((N_NODES + 31) / 32);
    dim3 gemm_block(64, 4);
    int edge_blocks = (N_EDGES * 64 + 255) / 256;
    int relu_blocks = (N_NODES * 64 / 4 + 255) / 256;

    // ---- layer 0: x -> h1 ----
    gemm_xb_root<<<gemm_grid, gemm_block, 0, stream>>>(x, basis, root, bias, xb, h1);
    edge_scatter<<<edge_blocks, 256, 0, stream>>>(ei, ea, att, xb, h1);
    relu_k<<<relu_blocks, 256, 0, stream>>>((float4*)h1, N_NODES * 64 / 4);

    // ---- layer 1: h1 -> out ----
    gemm_xb_root<<<gemm_grid, gemm_block, 0, stream>>>(h1, basis + 4 * 4096, root + 4096, bias + 64, xb, out);
    edge_scatter<<<edge_blocks, 256, 0, stream>>>(ei, ea, att + 32, xb, out);
}